// Round 9
// baseline (227.706 us; speedup 1.0000x reference)
//
#include <hip/hip_runtime.h>
#include <hip/hip_bf16.h>
#include <math.h>

// Problem constants
#define BATCH 8
#define SEQ   1024
#define CDIM  768
#define NH    12
#define HD    64
#define M_TOT (BATCH * SEQ)     // 8192
#define N_QKV (3 * CDIM)        // 2304
#define KDIM  768

typedef __attribute__((ext_vector_type(4))) _Float16 half4;
typedef __attribute__((ext_vector_type(8))) _Float16 half8;
typedef __attribute__((ext_vector_type(4))) float floatx4;

// ---------------------------------------------------------------------------
// async global->LDS, 16 B per lane. LDS dest = wave-uniform base + lane*16.
// ---------------------------------------------------------------------------
__device__ __forceinline__ void gld_lds16(const _Float16* g, _Float16* l) {
    __builtin_amdgcn_global_load_lds(
        (const __attribute__((address_space(1))) void*)g,
        (__attribute__((address_space(3))) void*)l, 16, 0, 0);
}

// v_exp_f32 is natively 2^x
__device__ __forceinline__ float exp2_fast(float x) {
#if __has_builtin(__builtin_amdgcn_exp2f)
    return __builtin_amdgcn_exp2f(x);
#else
    float r; asm("v_exp_f32 %0, %1" : "=v"(r) : "v"(x)); return r;
#endif
}

// ---------------------------------------------------------------------------
// fused fp32 -> fp16 convert for x / w_qkv / w_out (one launch)
// ---------------------------------------------------------------------------
__global__ __launch_bounds__(256) void cvt_all(
    const float* __restrict__ x, const float* __restrict__ wq,
    const float* __restrict__ wo,
    _Float16* __restrict__ x16, _Float16* __restrict__ wq16,
    _Float16* __restrict__ wo16)
{
    const int bid = blockIdx.x;
    const float* src; _Float16* dst; size_t base;
    if (bid < 6144)      { src = x;  dst = x16;  base = (size_t)bid * 1024; }
    else if (bid < 7872) { src = wq; dst = wq16; base = (size_t)(bid - 6144) * 1024; }
    else                 { src = wo; dst = wo16; base = (size_t)(bid - 7872) * 1024; }
    const size_t i = base + threadIdx.x * 4;
    float4 v = *reinterpret_cast<const float4*>(src + i);
    half4 h;
    h[0] = (_Float16)v.x; h[1] = (_Float16)v.y;
    h[2] = (_Float16)v.z; h[3] = (_Float16)v.w;
    *reinterpret_cast<half4*>(dst + i) = h;
}

// ===========================================================================
// QKV GEMM (NT): C[m,n] = sum_k A[m,k]*B[n,k] + bias[n]
//   128x128 tile, BK=64 single-stage DMA (measured: 0 bank conflicts; BK=32
//   dbuf regressed — 64B row stride aliases banks + 2x staging VALU).
//   Q/K blocks: mfma(bF,aF) -> C^T layout, reg r = consecutive n -> half4
//   row-major stores (16 x 8B instead of 64 x 2B).
//   V blocks: mfma(aF,bF) -> reg r = consecutive s -> fused-transpose half4
//   stores into VT[b][h][d][s].
//   grid: (N_QKV/128, M_TOT/128), block 256 (4 waves, 2x2 of 64x64)
// ===========================================================================
__global__ __launch_bounds__(256) void gemm_qkv(
    const _Float16* __restrict__ A, const _Float16* __restrict__ B,
    const float* __restrict__ bias, _Float16* __restrict__ C,
    _Float16* __restrict__ VT)
{
    __shared__ _Float16 Atile[128 * 64];
    __shared__ _Float16 Btile[128 * 64];
    const int tid  = threadIdx.x;
    const int wave = tid >> 6, lane = tid & 63, quad = lane >> 4, l16 = lane & 15;
    const int wm = wave >> 1, wn = wave & 1;
    const int m0 = blockIdx.y * 128, n0 = blockIdx.x * 128;
    const bool vreg = (n0 >= 2 * CDIM);

    const int strow = tid >> 3;               // 0..31
    const int scg   = (tid & 7) ^ (strow & 7);
    const _Float16* gA = A + (size_t)(m0 + strow) * KDIM + scg * 8;
    const _Float16* gB = B + (size_t)(n0 + strow) * KDIM + scg * 8;
    _Float16* lA = Atile + tid * 8;
    _Float16* lB = Btile + tid * 8;

    floatx4 acc[4][4];
#pragma unroll
    for (int i = 0; i < 4; ++i)
#pragma unroll
        for (int j = 0; j < 4; ++j) acc[i][j] = (floatx4){0.f, 0.f, 0.f, 0.f};

    for (int k0 = 0; k0 < KDIM; k0 += 64) {
        __syncthreads();
#pragma unroll
        for (int i = 0; i < 4; ++i) {
            gld_lds16(gA + (size_t)(i * 32) * KDIM + k0, lA + i * 2048);
            gld_lds16(gB + (size_t)(i * 32) * KDIM + k0, lB + i * 2048);
        }
        __syncthreads();
#pragma unroll
        for (int kk = 0; kk < 2; ++kk) {
            const int cg = (quad + kk * 4) ^ (l16 & 7);
            half8 aF[4], bF[4];
#pragma unroll
            for (int mt = 0; mt < 4; ++mt)
                aF[mt] = *reinterpret_cast<const half8*>(
                    &Atile[(wm * 64 + mt * 16 + l16) * 64 + cg * 8]);
#pragma unroll
            for (int nt = 0; nt < 4; ++nt)
                bF[nt] = *reinterpret_cast<const half8*>(
                    &Btile[(wn * 64 + nt * 16 + l16) * 64 + cg * 8]);
            if (!vreg) {
                // transposed placement: r = consecutive n, l16 = m
#pragma unroll
                for (int mt = 0; mt < 4; ++mt)
#pragma unroll
                    for (int nt = 0; nt < 4; ++nt)
                        acc[mt][nt] = __builtin_amdgcn_mfma_f32_16x16x32_f16(
                            bF[nt], aF[mt], acc[mt][nt], 0, 0, 0);
            } else {
                // standard placement: r = consecutive m (=s), l16 = n (=d)
#pragma unroll
                for (int mt = 0; mt < 4; ++mt)
#pragma unroll
                    for (int nt = 0; nt < 4; ++nt)
                        acc[mt][nt] = __builtin_amdgcn_mfma_f32_16x16x32_f16(
                            aF[mt], bF[nt], acc[mt][nt], 0, 0, 0);
            }
        }
    }

    if (!vreg) {
        // Q/K region: acc[mt][nt] holds C[m = m0+wm*64+mt*16+l16]
        //                              [n = n0+wn*64+nt*16+quad*4+r]
#pragma unroll
        for (int mt = 0; mt < 4; ++mt) {
            const int m = m0 + wm * 64 + mt * 16 + l16;
#pragma unroll
            for (int nt = 0; nt < 4; ++nt) {
                const int nb = n0 + wn * 64 + nt * 16 + quad * 4;
                const float4 bv = *reinterpret_cast<const float4*>(bias + nb);
                half4 hv;
                hv[0] = (_Float16)(acc[mt][nt][0] + bv.x);
                hv[1] = (_Float16)(acc[mt][nt][1] + bv.y);
                hv[2] = (_Float16)(acc[mt][nt][2] + bv.z);
                hv[3] = (_Float16)(acc[mt][nt][3] + bv.w);
                *reinterpret_cast<half4*>(&C[(size_t)m * N_QKV + nb]) = hv;
            }
        }
    } else {
        // V region: write transposed VT[b][h][d][s] (frag rows = contiguous s)
        const int bb = m0 >> 10;
#pragma unroll
        for (int nt = 0; nt < 4; ++nt) {
            const int colf = n0 + wn * 64 + nt * 16 + l16;
            const float bv = bias[colf];
            const int hd = colf - 2 * CDIM;
            const int hh = hd >> 6, d = hd & 63;
#pragma unroll
            for (int mt = 0; mt < 4; ++mt) {
                const int rowb = m0 + wm * 64 + mt * 16 + quad * 4;
                const int s = rowb & 1023;
                half4 hv;
#pragma unroll
                for (int r = 0; r < 4; ++r) hv[r] = (_Float16)(acc[mt][nt][r] + bv);
                *reinterpret_cast<half4*>(
                    &VT[((size_t)(bb * NH + hh) * HD + d) * SEQ + s]) = hv;
            }
        }
    }
}

// ===========================================================================
// Out-proj GEMM (NT): 64M x 128N tile, BK=64, swapped-operand epilogue ->
//   float4 row-major stores. fp32 out + bias.
//   grid: (CDIM/128, M_TOT/64) = 768 blocks
// ===========================================================================
__global__ __launch_bounds__(256) void gemm_out(
    const _Float16* __restrict__ A, const _Float16* __restrict__ B,
    const float* __restrict__ bias, float* __restrict__ C)
{
    __shared__ _Float16 Atile[64 * 64];
    __shared__ _Float16 Btile[128 * 64];
    const int tid  = threadIdx.x;
    const int wave = tid >> 6, lane = tid & 63, quad = lane >> 4, l16 = lane & 15;
    const int m0 = blockIdx.y * 64, n0 = blockIdx.x * 128;

    const int strow = tid >> 3;
    const int scg   = (tid & 7) ^ (strow & 7);
    const _Float16* gA = A + (size_t)(m0 + strow) * KDIM + scg * 8;
    const _Float16* gB = B + (size_t)(n0 + strow) * KDIM + scg * 8;
    _Float16* lA = Atile + tid * 8;
    _Float16* lB = Btile + tid * 8;

    floatx4 acc[8];
#pragma unroll
    for (int i = 0; i < 8; ++i) acc[i] = (floatx4){0.f, 0.f, 0.f, 0.f};

    for (int k0 = 0; k0 < KDIM; k0 += 64) {
        __syncthreads();
        gld_lds16(gA + k0, lA);
        gld_lds16(gA + (size_t)32 * KDIM + k0, lA + 2048);
#pragma unroll
        for (int i = 0; i < 4; ++i)
            gld_lds16(gB + (size_t)(i * 32) * KDIM + k0, lB + i * 2048);
        __syncthreads();
#pragma unroll
        for (int kk = 0; kk < 2; ++kk) {
            const int cg = (quad + kk * 4) ^ (l16 & 7);
            half8 aF = *reinterpret_cast<const half8*>(
                &Atile[(wave * 16 + l16) * 64 + cg * 8]);
            half8 bF[8];
#pragma unroll
            for (int nt = 0; nt < 8; ++nt)
                bF[nt] = *reinterpret_cast<const half8*>(
                    &Btile[(nt * 16 + l16) * 64 + cg * 8]);
#pragma unroll
            for (int nt = 0; nt < 8; ++nt)
                acc[nt] = __builtin_amdgcn_mfma_f32_16x16x32_f16(
                    bF[nt], aF, acc[nt], 0, 0, 0);   // r = consecutive n
        }
    }

    const int m = m0 + wave * 16 + l16;
#pragma unroll
    for (int nt = 0; nt < 8; ++nt) {
        const int nb = n0 + nt * 16 + quad * 4;
        const float4 bv = *reinterpret_cast<const float4*>(bias + nb);
        float4 o;
        o.x = acc[nt][0] + bv.x; o.y = acc[nt][1] + bv.y;
        o.z = acc[nt][2] + bv.z; o.w = acc[nt][3] + bv.w;
        *reinterpret_cast<float4*>(&C[(size_t)m * CDIM + nb]) = o;
    }
}

// ---------------------------------------------------------------------------
// Flash attention v4 (unchanged): async global_load_lds double-buffer,
// XOR-chunk swizzle in global pointers, exp2 fixed-max softmax, mask as int4
// regs, pkrtz packing. Block = pair {qt, 15-qt}; grid: (8, NH, BATCH), 256 thr
// ---------------------------------------------------------------------------
__global__ __launch_bounds__(256) void flash_attn(
    const _Float16* __restrict__ QKV, const _Float16* __restrict__ VT,
    const int* __restrict__ amask, _Float16* __restrict__ Y)
{
    __shared__ __align__(16) char smraw[32768];
    _Float16 (*Klds)[4096] = (_Float16 (*)[4096])smraw;              // 2 x 8 KB
    _Float16 (*Vlds)[4096] = (_Float16 (*)[4096])(smraw + 16384);    // 2 x 8 KB
    _Float16 (*osm)[72]    = (_Float16 (*)[72])smraw;                // epilogue alias

    const int qt = blockIdx.x, h = blockIdx.y, b = blockIdx.z;
    const int tid = threadIdx.x;
    const int w = tid >> 6, lane = tid & 63, quad = lane >> 4, l16 = lane & 15;
    const int qbA = qt * 64, qbB = (15 - qt) * 64;
    int qi[2] = { qbA + w * 16 + l16, qbB + w * 16 + l16 };

    const _Float16 qscale = (_Float16)0.18033688f;   // log2(e)/8
    half8 qf[2][2];
#pragma unroll
    for (int qg = 0; qg < 2; ++qg)
#pragma unroll
        for (int kc = 0; kc < 2; ++kc) {
            half8 q = *reinterpret_cast<const half8*>(
                QKV + (size_t)(b * SEQ + qi[qg]) * N_QKV + h * HD + kc * 32 + quad * 8);
#pragma unroll
            for (int i = 0; i < 8; ++i) q[i] = q[i] * qscale;
            qf[qg][kc] = q;
        }

    float rsum[2] = {0.f, 0.f};
    floatx4 accO[2][4];
#pragma unroll
    for (int qg = 0; qg < 2; ++qg)
#pragma unroll
        for (int dt = 0; dt < 4; ++dt) accO[qg][dt] = (floatx4){0.f, 0.f, 0.f, 0.f};

    const int srow0 = w * 16 + (lane >> 3);
    const int scg   = ((lane & 7) ^ (srow0 & 7)) * 8;
    const _Float16* gK = QKV + ((size_t)b * SEQ + srow0) * N_QKV + CDIM + h * HD + scg;
    const _Float16* gV = VT + ((size_t)(b * NH + h) * HD + srow0) * SEQ + scg;

    const int nt = 16 - qt;

    gld_lds16(gK,             &Klds[0][w * 1024]);
    gld_lds16(gK + 8 * N_QKV, &Klds[0][w * 1024 + 512]);
    gld_lds16(gV,             &Vlds[0][w * 1024]);
    gld_lds16(gV + 8 * SEQ,   &Vlds[0][w * 1024 + 512]);
    int4 mcur[4];
#pragma unroll
    for (int kt = 0; kt < 4; ++kt)
        mcur[kt] = *reinterpret_cast<const int4*>(&amask[b * SEQ + kt * 16 + quad * 4]);

    for (int t = 0; t < nt; ++t) {
        const int buf = t & 1, nbuf = buf ^ 1;
        const int t0 = t * 64;
        const bool actA = (t <= qt), fullA = (t < qt), fullB = (t + qt < 15);

        __syncthreads();

        int4 mnext[4];
        if (t + 1 < nt) {
            const int t1 = t0 + 64;
            gld_lds16(gK + (size_t)t1 * N_QKV,       &Klds[nbuf][w * 1024]);
            gld_lds16(gK + (size_t)(t1 + 8) * N_QKV, &Klds[nbuf][w * 1024 + 512]);
            gld_lds16(gV + t1,                       &Vlds[nbuf][w * 1024]);
            gld_lds16(gV + t1 + 8 * SEQ,             &Vlds[nbuf][w * 1024 + 512]);
#pragma unroll
            for (int kt = 0; kt < 4; ++kt)
                mnext[kt] = *reinterpret_cast<const int4*>(
                    &amask[b * SEQ + t1 + kt * 16 + quad * 4]);
        }

        float bias[4][4];
#pragma unroll
        for (int kt = 0; kt < 4; ++kt) {
            bias[kt][0] = mcur[kt].x ? 0.f : -1e30f;
            bias[kt][1] = mcur[kt].y ? 0.f : -1e30f;
            bias[kt][2] = mcur[kt].z ? 0.f : -1e30f;
            bias[kt][3] = mcur[kt].w ? 0.f : -1e30f;
        }

        half4 pfA[4], pfB[4];
#pragma unroll
        for (int kt = 0; kt < 4; ++kt) {
            floatx4 aS0 = (floatx4){0.f, 0.f, 0.f, 0.f};
            floatx4 aS1 = (floatx4){0.f, 0.f, 0.f, 0.f};
            const int krow = kt * 16 + l16;
#pragma unroll
            for (int kc = 0; kc < 2; ++kc) {
                half8 kf = *reinterpret_cast<const half8*>(
                    &Klds[buf][krow * 64 + (((kc * 4 + quad) ^ (krow & 7)) * 8)]);
                if (actA) aS0 = __builtin_amdgcn_mfma_f32_16x16x32_f16(kf, qf[0][kc], aS0, 0, 0, 0);
                aS1 = __builtin_amdgcn_mfma_f32_16x16x32_f16(kf, qf[1][kc], aS1, 0, 0, 0);
            }
            float pA[4], pB[4];
#pragma unroll
            for (int r = 0; r < 4; ++r) {
                const int key = t0 + kt * 16 + quad * 4 + r;
                float sB = aS1[r] + bias[kt][r];
                if (!fullB && key > qi[1]) sB = -1e30f;
                pB[r] = exp2_fast(sB);
                if (actA) {
                    float sA = aS0[r] + bias[kt][r];
                    if (!fullA && key > qi[0]) sA = -1e30f;
                    pA[r] = exp2_fast(sA);
                }
            }
            rsum[1] += (pB[0] + pB[1]) + (pB[2] + pB[3]);
            {
                auto lo = __builtin_amdgcn_cvt_pkrtz(pB[0], pB[1]);
                auto hi = __builtin_amdgcn_cvt_pkrtz(pB[2], pB[3]);
                half4 pf; pf[0] = lo[0]; pf[1] = lo[1]; pf[2] = hi[0]; pf[3] = hi[1];
                pfB[kt] = pf;
            }
            if (actA) {
                rsum[0] += (pA[0] + pA[1]) + (pA[2] + pA[3]);
                auto lo = __builtin_amdgcn_cvt_pkrtz(pA[0], pA[1]);
                auto hi = __builtin_amdgcn_cvt_pkrtz(pA[2], pA[3]);
                half4 pf; pf[0] = lo[0]; pf[1] = lo[1]; pf[2] = hi[0]; pf[3] = hi[1];
                pfA[kt] = pf;
            }
        }

#pragma unroll
        for (int dt = 0; dt < 4; ++dt) {
            const int vrow = dt * 16 + l16;
#pragma unroll
            for (int kt = 0; kt < 4; ++kt) {
                half4 vf = *reinterpret_cast<const half4*>(
                    &Vlds[buf][vrow * 64 +
                               (((kt * 2 + (quad >> 1)) ^ (vrow & 7)) * 8) +
                               (quad & 1) * 4]);
                if (actA) accO[0][dt] = __builtin_amdgcn_mfma_f32_16x16x16f16(
                    vf, pfA[kt], accO[0][dt], 0, 0, 0);
                accO[1][dt] = __builtin_amdgcn_mfma_f32_16x16x16f16(
                    vf, pfB[kt], accO[1][dt], 0, 0, 0);
            }
        }

        if (t + 1 < nt) {
#pragma unroll
            for (int kt = 0; kt < 4; ++kt) mcur[kt] = mnext[kt];
        }
    }

    float inv[2];
#pragma unroll
    for (int qg = 0; qg < 2; ++qg) {
        float l = rsum[qg];
        l += __shfl_xor(l, 16, 64);
        l += __shfl_xor(l, 32, 64);
        inv[qg] = (l > 0.f) ? 1.f / l : 0.f;
    }

    __syncthreads();
#pragma unroll
    for (int qg = 0; qg < 2; ++qg)
#pragma unroll
        for (int dt = 0; dt < 4; ++dt)
#pragma unroll
            for (int r = 0; r < 4; ++r)
                osm[qg * 64 + w * 16 + l16][dt * 16 + quad * 4 + r] =
                    (_Float16)(accO[qg][dt][r] * inv[qg]);
    __syncthreads();

    const int q  = tid >> 1;
    const int dc = (tid & 1) * 32;
    const int grow = (q < 64) ? (qbA + q) : (qbB + q - 64);
    _Float16* dst = Y + ((size_t)(b * SEQ + grow)) * CDIM + h * HD + dc;
#pragma unroll
    for (int i = 0; i < 4; ++i)
        *reinterpret_cast<half8*>(dst + 8 * i) =
            *reinterpret_cast<const half8*>(&osm[q][dc + 8 * i]);
}

// ---------------------------------------------------------------------------
extern "C" void kernel_launch(void* const* d_in, const int* in_sizes, int n_in,
                              void* d_out, int out_size, void* d_ws, size_t ws_size,
                              hipStream_t stream)
{
    const float* x      = (const float*)d_in[0];  // [8, 1024, 768]
    const float* w_qkv  = (const float*)d_in[1];  // [2304, 768]
    const float* b_qkv  = (const float*)d_in[2];  // [2304]
    const float* w_out  = (const float*)d_in[3];  // [768, 768]
    const float* b_out  = (const float*)d_in[4];  // [768]
    const int*   amask  = (const int*)d_in[5];    // [8, 1024]
    float* out = (float*)d_out;                   // [8, 1024, 768]

    _Float16* ws = (_Float16*)d_ws;
    _Float16* x16    = ws;                               //  6,291,456
    _Float16* wqkv16 = x16 + (size_t)M_TOT * CDIM;       //  1,769,472
    _Float16* wout16 = wqkv16 + (size_t)N_QKV * CDIM;    //    589,824
    _Float16* qkv16  = wout16 + (size_t)CDIM * CDIM;     // 18,874,368 (V region unused)
    _Float16* y16    = qkv16 + (size_t)M_TOT * N_QKV;    //  6,291,456
    _Float16* VT     = y16 + (size_t)M_TOT * CDIM;       //  6,291,456

    cvt_all<<<8448, 256, 0, stream>>>(x, w_qkv, w_out, x16, wqkv16, wout16);

    gemm_qkv<<<dim3(N_QKV / 128, M_TOT / 128), 256, 0, stream>>>(
        x16, wqkv16, b_qkv, qkv16, VT);
    flash_attn<<<dim3(8, NH, BATCH), 256, 0, stream>>>(
        qkv16, VT, amask, y16);
    gemm_out<<<dim3(CDIM / 128, M_TOT / 64), 256, 0, stream>>>(
        y16, wout16, b_out, out);
}

// Round 10
// 198.509 us; speedup vs baseline: 1.1471x; 1.1471x over previous
//
#include <hip/hip_runtime.h>
#include <hip/hip_bf16.h>
#include <math.h>

// Problem constants
#define BATCH 8
#define SEQ   1024
#define CDIM  768
#define NH    12
#define HD    64
#define M_TOT (BATCH * SEQ)     // 8192
#define N_QKV (3 * CDIM)        // 2304
#define KDIM  768

typedef __attribute__((ext_vector_type(4))) _Float16 half4;
typedef __attribute__((ext_vector_type(8))) _Float16 half8;
typedef __attribute__((ext_vector_type(4))) float floatx4;

// ---------------------------------------------------------------------------
// async global->LDS, 16 B per lane. LDS dest = wave-uniform base + lane*16.
// ---------------------------------------------------------------------------
__device__ __forceinline__ void gld_lds16(const _Float16* g, _Float16* l) {
    __builtin_amdgcn_global_load_lds(
        (const __attribute__((address_space(1))) void*)g,
        (__attribute__((address_space(3))) void*)l, 16, 0, 0);
}

// v_exp_f32 is natively 2^x
__device__ __forceinline__ float exp2_fast(float x) {
#if __has_builtin(__builtin_amdgcn_exp2f)
    return __builtin_amdgcn_exp2f(x);
#else
    float r; asm("v_exp_f32 %0, %1" : "=v"(r) : "v"(x)); return r;
#endif
}

// ---------------------------------------------------------------------------
// fused fp32 -> fp16 convert for x / w_qkv / w_out (one launch)
// ---------------------------------------------------------------------------
__global__ __launch_bounds__(256) void cvt_all(
    const float* __restrict__ x, const float* __restrict__ wq,
    const float* __restrict__ wo,
    _Float16* __restrict__ x16, _Float16* __restrict__ wq16,
    _Float16* __restrict__ wo16)
{
    const int bid = blockIdx.x;
    const float* src; _Float16* dst; size_t base;
    if (bid < 6144)      { src = x;  dst = x16;  base = (size_t)bid * 1024; }
    else if (bid < 7872) { src = wq; dst = wq16; base = (size_t)(bid - 6144) * 1024; }
    else                 { src = wo; dst = wo16; base = (size_t)(bid - 7872) * 1024; }
    const size_t i = base + threadIdx.x * 4;
    float4 v = *reinterpret_cast<const float4*>(src + i);
    half4 h;
    h[0] = (_Float16)v.x; h[1] = (_Float16)v.y;
    h[2] = (_Float16)v.z; h[3] = (_Float16)v.w;
    *reinterpret_cast<half4*>(dst + i) = h;
}

// ===========================================================================
// QKV GEMM (NT): C[m,n] = sum_k A[m,k]*B[n,k] + bias[n]  (R7 structure:
//   128x128 tile, BK=64 single-stage DMA, 0 bank conflicts, uniform epilogue)
//   + XCD-aware block remap: all 18 n-blocks of an m-tile land on one XCD
//   (L2 A-reuse; A-tile fetched once instead of up to 8x).
//   Q/K cols -> qkv16 row-major; V cols -> VT[b][h][d][s] (fused transpose).
//   grid: 1152 linear, block 256 (4 waves, 2x2 of 64x64)
// ===========================================================================
__global__ __launch_bounds__(256) void gemm_qkv(
    const _Float16* __restrict__ A, const _Float16* __restrict__ B,
    const float* __restrict__ bias, _Float16* __restrict__ C,
    _Float16* __restrict__ VT)
{
    __shared__ _Float16 Atile[128 * 64];
    __shared__ _Float16 Btile[128 * 64];
    const int tid  = threadIdx.x;
    const int wave = tid >> 6, lane = tid & 63, quad = lane >> 4, l16 = lane & 15;
    const int wm = wave >> 1, wn = wave & 1;
    // XCD remap: L%8 = XCD (assumed round-robin); same-m blocks share an XCD.
    const int L = blockIdx.x;
    const int g = L & 7, i = L >> 3;            // i in 0..143
    const int m0 = (g * 8 + i / 18) * 128;      // 64 m-tiles
    const int n0 = (i % 18) * 128;              // 18 n-tiles

    const int strow = tid >> 3;               // 0..31
    const int scg   = (tid & 7) ^ (strow & 7);
    const _Float16* gA = A + (size_t)(m0 + strow) * KDIM + scg * 8;
    const _Float16* gB = B + (size_t)(n0 + strow) * KDIM + scg * 8;
    _Float16* lA = Atile + tid * 8;
    _Float16* lB = Btile + tid * 8;

    floatx4 acc[4][4];
#pragma unroll
    for (int i2 = 0; i2 < 4; ++i2)
#pragma unroll
        for (int j = 0; j < 4; ++j) acc[i2][j] = (floatx4){0.f, 0.f, 0.f, 0.f};

    for (int k0 = 0; k0 < KDIM; k0 += 64) {
        __syncthreads();
#pragma unroll
        for (int it = 0; it < 4; ++it) {
            gld_lds16(gA + (size_t)(it * 32) * KDIM + k0, lA + it * 2048);
            gld_lds16(gB + (size_t)(it * 32) * KDIM + k0, lB + it * 2048);
        }
        __syncthreads();
#pragma unroll
        for (int kk = 0; kk < 2; ++kk) {
            const int cg = (quad + kk * 4) ^ (l16 & 7);
            half8 aF[4], bF[4];
#pragma unroll
            for (int mt = 0; mt < 4; ++mt)
                aF[mt] = *reinterpret_cast<const half8*>(
                    &Atile[(wm * 64 + mt * 16 + l16) * 64 + cg * 8]);
#pragma unroll
            for (int nt = 0; nt < 4; ++nt)
                bF[nt] = *reinterpret_cast<const half8*>(
                    &Btile[(wn * 64 + nt * 16 + l16) * 64 + cg * 8]);
#pragma unroll
            for (int mt = 0; mt < 4; ++mt)
#pragma unroll
                for (int nt = 0; nt < 4; ++nt)
                    acc[mt][nt] = __builtin_amdgcn_mfma_f32_16x16x32_f16(
                        aF[mt], bF[nt], acc[mt][nt], 0, 0, 0);
        }
    }

    if (n0 < 2 * CDIM) {
        // Q / K region: plain row-major fp16 store into qkv16
#pragma unroll
        for (int nt = 0; nt < 4; ++nt) {
            const int col = n0 + wn * 64 + nt * 16 + l16;
            const float bv = bias[col];
#pragma unroll
            for (int mt = 0; mt < 4; ++mt) {
                const int rowb = m0 + wm * 64 + mt * 16 + quad * 4;
#pragma unroll
                for (int r = 0; r < 4; ++r)
                    C[(size_t)(rowb + r) * N_QKV + col] = (_Float16)(acc[mt][nt][r] + bv);
            }
        }
    } else {
        // V region: write transposed VT[b][h][d][s] (frag rows = contiguous s)
        const int bb = m0 >> 10;
#pragma unroll
        for (int nt = 0; nt < 4; ++nt) {
            const int colf = n0 + wn * 64 + nt * 16 + l16;
            const float bv = bias[colf];
            const int hd = colf - 2 * CDIM;
            const int hh = hd >> 6, d = hd & 63;
#pragma unroll
            for (int mt = 0; mt < 4; ++mt) {
                const int rowb = m0 + wm * 64 + mt * 16 + quad * 4;
                const int s = rowb & 1023;
                half4 hv;
#pragma unroll
                for (int r = 0; r < 4; ++r) hv[r] = (_Float16)(acc[mt][nt][r] + bv);
                *reinterpret_cast<half4*>(
                    &VT[((size_t)(bb * NH + hh) * HD + d) * SEQ + s]) = hv;
            }
        }
    }
}

// ===========================================================================
// Out-proj GEMM (NT): 64M x 128N tile, BK=64 (R7 structure) + XCD remap
//   (768 = 8 x 96; all 6 n-blocks of an m-tile on one XCD). fp32 out + bias.
//   grid: 768 linear
// ===========================================================================
__global__ __launch_bounds__(256) void gemm_out(
    const _Float16* __restrict__ A, const _Float16* __restrict__ B,
    const float* __restrict__ bias, float* __restrict__ C)
{
    __shared__ _Float16 Atile[64 * 64];
    __shared__ _Float16 Btile[128 * 64];
    const int tid  = threadIdx.x;
    const int wave = tid >> 6, lane = tid & 63, quad = lane >> 4, l16 = lane & 15;
    const int L = blockIdx.x;
    const int g = L & 7, i = L >> 3;            // i in 0..95
    const int m0 = (g * 16 + i / 6) * 64;       // 128 m-tiles
    const int n0 = (i % 6) * 128;               // 6 n-tiles

    const int strow = tid >> 3;
    const int scg   = (tid & 7) ^ (strow & 7);
    const _Float16* gA = A + (size_t)(m0 + strow) * KDIM + scg * 8;
    const _Float16* gB = B + (size_t)(n0 + strow) * KDIM + scg * 8;
    _Float16* lA = Atile + tid * 8;
    _Float16* lB = Btile + tid * 8;

    floatx4 acc[8];
#pragma unroll
    for (int i2 = 0; i2 < 8; ++i2) acc[i2] = (floatx4){0.f, 0.f, 0.f, 0.f};

    for (int k0 = 0; k0 < KDIM; k0 += 64) {
        __syncthreads();
        gld_lds16(gA + k0, lA);
        gld_lds16(gA + (size_t)32 * KDIM + k0, lA + 2048);
#pragma unroll
        for (int it = 0; it < 4; ++it)
            gld_lds16(gB + (size_t)(it * 32) * KDIM + k0, lB + it * 2048);
        __syncthreads();
#pragma unroll
        for (int kk = 0; kk < 2; ++kk) {
            const int cg = (quad + kk * 4) ^ (l16 & 7);
            half8 aF = *reinterpret_cast<const half8*>(
                &Atile[(wave * 16 + l16) * 64 + cg * 8]);
            half8 bF[8];
#pragma unroll
            for (int nt = 0; nt < 8; ++nt)
                bF[nt] = *reinterpret_cast<const half8*>(
                    &Btile[(nt * 16 + l16) * 64 + cg * 8]);
#pragma unroll
            for (int nt = 0; nt < 8; ++nt)
                acc[nt] = __builtin_amdgcn_mfma_f32_16x16x32_f16(
                    aF, bF[nt], acc[nt], 0, 0, 0);
        }
    }

#pragma unroll
    for (int nt = 0; nt < 8; ++nt) {
        const int col = n0 + nt * 16 + l16;
        const float bv = bias[col];
        const int rowb = m0 + wave * 16 + quad * 4;
#pragma unroll
        for (int r = 0; r < 4; ++r)
            C[(size_t)(rowb + r) * CDIM + col] = acc[nt][r] + bv;
    }
}

// ---------------------------------------------------------------------------
// Flash attention v4 (unchanged from R7): async global_load_lds double-buffer,
// XOR-chunk swizzle in global pointers, exp2 fixed-max softmax, mask as int4
// regs, pkrtz packing. Block = pair {qt, 15-qt}; grid: (8, NH, BATCH), 256 thr
// ---------------------------------------------------------------------------
__global__ __launch_bounds__(256) void flash_attn(
    const _Float16* __restrict__ QKV, const _Float16* __restrict__ VT,
    const int* __restrict__ amask, _Float16* __restrict__ Y)
{
    __shared__ __align__(16) char smraw[32768];
    _Float16 (*Klds)[4096] = (_Float16 (*)[4096])smraw;              // 2 x 8 KB
    _Float16 (*Vlds)[4096] = (_Float16 (*)[4096])(smraw + 16384);    // 2 x 8 KB
    _Float16 (*osm)[72]    = (_Float16 (*)[72])smraw;                // epilogue alias

    const int qt = blockIdx.x, h = blockIdx.y, b = blockIdx.z;
    const int tid = threadIdx.x;
    const int w = tid >> 6, lane = tid & 63, quad = lane >> 4, l16 = lane & 15;
    const int qbA = qt * 64, qbB = (15 - qt) * 64;
    int qi[2] = { qbA + w * 16 + l16, qbB + w * 16 + l16 };

    const _Float16 qscale = (_Float16)0.18033688f;   // log2(e)/8
    half8 qf[2][2];
#pragma unroll
    for (int qg = 0; qg < 2; ++qg)
#pragma unroll
        for (int kc = 0; kc < 2; ++kc) {
            half8 q = *reinterpret_cast<const half8*>(
                QKV + (size_t)(b * SEQ + qi[qg]) * N_QKV + h * HD + kc * 32 + quad * 8);
#pragma unroll
            for (int i = 0; i < 8; ++i) q[i] = q[i] * qscale;
            qf[qg][kc] = q;
        }

    float rsum[2] = {0.f, 0.f};
    floatx4 accO[2][4];
#pragma unroll
    for (int qg = 0; qg < 2; ++qg)
#pragma unroll
        for (int dt = 0; dt < 4; ++dt) accO[qg][dt] = (floatx4){0.f, 0.f, 0.f, 0.f};

    const int srow0 = w * 16 + (lane >> 3);
    const int scg   = ((lane & 7) ^ (srow0 & 7)) * 8;
    const _Float16* gK = QKV + ((size_t)b * SEQ + srow0) * N_QKV + CDIM + h * HD + scg;
    const _Float16* gV = VT + ((size_t)(b * NH + h) * HD + srow0) * SEQ + scg;

    const int nt = 16 - qt;

    gld_lds16(gK,             &Klds[0][w * 1024]);
    gld_lds16(gK + 8 * N_QKV, &Klds[0][w * 1024 + 512]);
    gld_lds16(gV,             &Vlds[0][w * 1024]);
    gld_lds16(gV + 8 * SEQ,   &Vlds[0][w * 1024 + 512]);
    int4 mcur[4];
#pragma unroll
    for (int kt = 0; kt < 4; ++kt)
        mcur[kt] = *reinterpret_cast<const int4*>(&amask[b * SEQ + kt * 16 + quad * 4]);

    for (int t = 0; t < nt; ++t) {
        const int buf = t & 1, nbuf = buf ^ 1;
        const int t0 = t * 64;
        const bool actA = (t <= qt), fullA = (t < qt), fullB = (t + qt < 15);

        __syncthreads();

        int4 mnext[4];
        if (t + 1 < nt) {
            const int t1 = t0 + 64;
            gld_lds16(gK + (size_t)t1 * N_QKV,       &Klds[nbuf][w * 1024]);
            gld_lds16(gK + (size_t)(t1 + 8) * N_QKV, &Klds[nbuf][w * 1024 + 512]);
            gld_lds16(gV + t1,                       &Vlds[nbuf][w * 1024]);
            gld_lds16(gV + t1 + 8 * SEQ,             &Vlds[nbuf][w * 1024 + 512]);
#pragma unroll
            for (int kt = 0; kt < 4; ++kt)
                mnext[kt] = *reinterpret_cast<const int4*>(
                    &amask[b * SEQ + t1 + kt * 16 + quad * 4]);
        }

        float bias[4][4];
#pragma unroll
        for (int kt = 0; kt < 4; ++kt) {
            bias[kt][0] = mcur[kt].x ? 0.f : -1e30f;
            bias[kt][1] = mcur[kt].y ? 0.f : -1e30f;
            bias[kt][2] = mcur[kt].z ? 0.f : -1e30f;
            bias[kt][3] = mcur[kt].w ? 0.f : -1e30f;
        }

        half4 pfA[4], pfB[4];
#pragma unroll
        for (int kt = 0; kt < 4; ++kt) {
            floatx4 aS0 = (floatx4){0.f, 0.f, 0.f, 0.f};
            floatx4 aS1 = (floatx4){0.f, 0.f, 0.f, 0.f};
            const int krow = kt * 16 + l16;
#pragma unroll
            for (int kc = 0; kc < 2; ++kc) {
                half8 kf = *reinterpret_cast<const half8*>(
                    &Klds[buf][krow * 64 + (((kc * 4 + quad) ^ (krow & 7)) * 8)]);
                if (actA) aS0 = __builtin_amdgcn_mfma_f32_16x16x32_f16(kf, qf[0][kc], aS0, 0, 0, 0);
                aS1 = __builtin_amdgcn_mfma_f32_16x16x32_f16(kf, qf[1][kc], aS1, 0, 0, 0);
            }
            float pA[4], pB[4];
#pragma unroll
            for (int r = 0; r < 4; ++r) {
                const int key = t0 + kt * 16 + quad * 4 + r;
                float sB = aS1[r] + bias[kt][r];
                if (!fullB && key > qi[1]) sB = -1e30f;
                pB[r] = exp2_fast(sB);
                if (actA) {
                    float sA = aS0[r] + bias[kt][r];
                    if (!fullA && key > qi[0]) sA = -1e30f;
                    pA[r] = exp2_fast(sA);
                }
            }
            rsum[1] += (pB[0] + pB[1]) + (pB[2] + pB[3]);
            {
                auto lo = __builtin_amdgcn_cvt_pkrtz(pB[0], pB[1]);
                auto hi = __builtin_amdgcn_cvt_pkrtz(pB[2], pB[3]);
                half4 pf; pf[0] = lo[0]; pf[1] = lo[1]; pf[2] = hi[0]; pf[3] = hi[1];
                pfB[kt] = pf;
            }
            if (actA) {
                rsum[0] += (pA[0] + pA[1]) + (pA[2] + pA[3]);
                auto lo = __builtin_amdgcn_cvt_pkrtz(pA[0], pA[1]);
                auto hi = __builtin_amdgcn_cvt_pkrtz(pA[2], pA[3]);
                half4 pf; pf[0] = lo[0]; pf[1] = lo[1]; pf[2] = hi[0]; pf[3] = hi[1];
                pfA[kt] = pf;
            }
        }

#pragma unroll
        for (int dt = 0; dt < 4; ++dt) {
            const int vrow = dt * 16 + l16;
#pragma unroll
            for (int kt = 0; kt < 4; ++kt) {
                half4 vf = *reinterpret_cast<const half4*>(
                    &Vlds[buf][vrow * 64 +
                               (((kt * 2 + (quad >> 1)) ^ (vrow & 7)) * 8) +
                               (quad & 1) * 4]);
                if (actA) accO[0][dt] = __builtin_amdgcn_mfma_f32_16x16x16f16(
                    vf, pfA[kt], accO[0][dt], 0, 0, 0);
                accO[1][dt] = __builtin_amdgcn_mfma_f32_16x16x16f16(
                    vf, pfB[kt], accO[1][dt], 0, 0, 0);
            }
        }

        if (t + 1 < nt) {
#pragma unroll
            for (int kt = 0; kt < 4; ++kt) mcur[kt] = mnext[kt];
        }
    }

    float inv[2];
#pragma unroll
    for (int qg = 0; qg < 2; ++qg) {
        float l = rsum[qg];
        l += __shfl_xor(l, 16, 64);
        l += __shfl_xor(l, 32, 64);
        inv[qg] = (l > 0.f) ? 1.f / l : 0.f;
    }

    __syncthreads();
#pragma unroll
    for (int qg = 0; qg < 2; ++qg)
#pragma unroll
        for (int dt = 0; dt < 4; ++dt)
#pragma unroll
            for (int r = 0; r < 4; ++r)
                osm[qg * 64 + w * 16 + l16][dt * 16 + quad * 4 + r] =
                    (_Float16)(accO[qg][dt][r] * inv[qg]);
    __syncthreads();

    const int q  = tid >> 1;
    const int dc = (tid & 1) * 32;
    const int grow = (q < 64) ? (qbA + q) : (qbB + q - 64);
    _Float16* dst = Y + ((size_t)(b * SEQ + grow)) * CDIM + h * HD + dc;
#pragma unroll
    for (int i = 0; i < 4; ++i)
        *reinterpret_cast<half8*>(dst + 8 * i) =
            *reinterpret_cast<const half8*>(&osm[q][dc + 8 * i]);
}

// ---------------------------------------------------------------------------
extern "C" void kernel_launch(void* const* d_in, const int* in_sizes, int n_in,
                              void* d_out, int out_size, void* d_ws, size_t ws_size,
                              hipStream_t stream)
{
    const float* x      = (const float*)d_in[0];  // [8, 1024, 768]
    const float* w_qkv  = (const float*)d_in[1];  // [2304, 768]
    const float* b_qkv  = (const float*)d_in[2];  // [2304]
    const float* w_out  = (const float*)d_in[3];  // [768, 768]
    const float* b_out  = (const float*)d_in[4];  // [768]
    const int*   amask  = (const int*)d_in[5];    // [8, 1024]
    float* out = (float*)d_out;                   // [8, 1024, 768]

    _Float16* ws = (_Float16*)d_ws;
    _Float16* x16    = ws;                               //  6,291,456
    _Float16* wqkv16 = x16 + (size_t)M_TOT * CDIM;       //  1,769,472
    _Float16* wout16 = wqkv16 + (size_t)N_QKV * CDIM;    //    589,824
    _Float16* qkv16  = wout16 + (size_t)CDIM * CDIM;     // 18,874,368 (V region unused)
    _Float16* y16    = qkv16 + (size_t)M_TOT * N_QKV;    //  6,291,456
    _Float16* VT     = y16 + (size_t)M_TOT * CDIM;       //  6,291,456

    cvt_all<<<8448, 256, 0, stream>>>(x, w_qkv, w_out, x16, wqkv16, wout16);

    gemm_qkv<<<1152, 256, 0, stream>>>(
        x16, wqkv16, b_qkv, qkv16, VT);
    flash_attn<<<dim3(8, NH, BATCH), 256, 0, stream>>>(
        qkv16, VT, amask, y16);
    gemm_out<<<768, 256, 0, stream>>>(
        y16, wout16, b_out, out);
}